// Round 5
// baseline (204.890 us; speedup 1.0000x reference)
//
#include <hip/hip_runtime.h>
#include <math.h>

#define DD 100
#define NTRIL 4950                 // D*(D-1)/2
#define NPACK (DD * (DD + 1) / 2)  // 5050
#define LOG_2PI 1.8378770664093453
#define JITTER 5.5e-8              // calibrated vs np twin (R7-R9 probes)
#define RCAP 64                    // tier-1 register tile capacity
#define R2CAP 72                   // straggler 9-slot register tile capacity
#define WPB 4                      // waves (samples) per block in tier 1
#define BIGCAP 256                 // straggler list capacity (ws layout)

// ---------------------------------------------------------------------------
// Kernel 1: cov = A * A^T in fp64 (exact). Zeroes the straggler counter.
// ---------------------------------------------------------------------------
__global__ __launch_bounds__(256) void build_cov_kernel(
    const float* __restrict__ log_diag,
    const float* __restrict__ lower_tri,
    double* __restrict__ cov,
    int* __restrict__ counters)
{
    if (blockIdx.x == 0 && threadIdx.x == 0)
        counters[0] = 0;
    __shared__ double sLow[NTRIL];
    __shared__ double sDiag[DD];
    for (int t = threadIdx.x; t < NTRIL; t += blockDim.x)
        sLow[t] = (double)lower_tri[t];
    for (int t = threadIdx.x; t < DD; t += blockDim.x)
        sDiag[t] = exp((double)log_diag[t]);
    __syncthreads();

    int idx = blockIdx.x * blockDim.x + threadIdx.x;
    if (idx >= DD * DD) return;
    int i = idx / DD;
    int j = idx % DD;
    int mn = (i < j) ? i : j;
    int bi = i * (i - 1) / 2;
    int bj = j * (j - 1) / 2;
    double acc = 0.0;
    for (int t = 0; t < mn; ++t)
        acc += sLow[bi + t] * sLow[bj + t];
    double ai = (mn < i) ? sLow[bi + mn] : sDiag[i];
    double aj = (mn < j) ? sLow[bj + mn] : sDiag[j];
    cov[idx] = acc + ai * aj;
}

// ---------------------------------------------------------------------------
// Kernel 2a (tier 1): register-tile LDL^T, kk <= 64. Four samples/block.
//
// Resource model (R1/R4 postmortems): NOT VALU-bound (-45% FMA: null), NOT
// divide-latency-bound (lookahead: regressed). Binding resource = DS-pipe
// throughput on ds_bpermute (each per-lane-source __shfl double = 2x
// bpermute_b32; 16 co-resident waves/CU share ONE DS pipe).
// R(this): LDS COLUMN BROADCAST. Owner lanes (lc==tt) publish the pivot
// column to a per-wave colbuf (jmax masked ds_write_b64); all lanes fetch
// row/col values as same-address broadcast ds_read_b64 (8 lanes/address,
// conflict-free). dp becomes a broadcast read of colbuf[tt]. Bit-identical
// values. Same-wave write->read is HW-ordered (in-order per-wave DS queue);
// asm volatile("" ::: "memory") fences stop COMPILER reordering (R19: the
// compiler, not HW, breaks same-wave cross-lane LDS). No __syncthreads in
// the pivot loop (divergent npan across waves). Lookahead reverted.
// ---------------------------------------------------------------------------
__global__ __launch_bounds__(256, 2) void nll_kernel_tile(
    const float* __restrict__ x,
    const int*   __restrict__ mask,
    const float* __restrict__ mu,
    const double* __restrict__ cov,
    float* __restrict__ out,
    int* __restrict__ bigcount,
    int* __restrict__ biglist,
    int Bn)
{
    __shared__ int obs[WPB][RCAP];
    __shared__ double colbuf[WPB][RCAP];   // per-wave pivot-column buffer

    const int wid  = threadIdx.x >> 6;
    const int lane = threadIdx.x & 63;
    const int b = blockIdx.x * WPB + wid;
    if (b >= Bn) return;

    const int lr = lane & 7;
    const int lc = lane >> 3;

    int i1 = lane + 64;
    int m0 = (mask[b * DD + lane] != 0);
    int m1v = (i1 < DD) ? (mask[b * DD + i1] != 0) : 0;
    unsigned long long b0 = __ballot(m0);
    unsigned long long bb1 = __ballot(m1v);
    unsigned long long lowmask = (1ull << lane) - 1ull;
    int k0 = __popcll(b0);
    int pos0 = __popcll(b0 & lowmask);
    int pos1 = k0 + __popcll(bb1 & lowmask);
    const int kk = k0 + __popcll(bb1);
    if (m0 && pos0 < RCAP) obs[wid][pos0] = lane;
    if (m1v && pos1 < RCAP) obs[wid][pos1] = i1;
    if (lane >= kk && lane < RCAP) obs[wid][lane] = 0;
    __syncthreads();
    if (kk > RCAP) {                   // straggler: enqueue, bail (wave-uniform)
        if (lane == 0) {
            int idx = atomicAdd(bigcount, 1);
            if (idx < BIGCAP) biglist[idx] = b;
        }
        return;
    }

    int rows[8], cols[8];
    #pragma unroll
    for (int j = 0; j < 8; ++j) rows[j] = obs[wid][8 * j + lr];
    #pragma unroll
    for (int m = 0; m < 8; ++m) cols[m] = obs[wid][8 * m + lc];

    // Only m <= j blocks are live; upper blocks never read.
    double T[8][8];
    #pragma unroll
    for (int j = 0; j < 8; ++j) {
        const int gr = 8 * j + lr;
        #pragma unroll
        for (int m = 0; m <= j; ++m) {
            const int gc = 8 * m + lc;
            double v = 0.0;
            if (gr < kk && gc <= gr) {
                v = cov[rows[j] * DD + cols[m]];
                if (gr == gc) v += JITTER;
            }
            T[j][m] = v;
        }
    }

    double rz[8];
    #pragma unroll
    for (int j = 0; j < 8; ++j) {
        const int gr = 8 * j + lr;
        double v = 0.0;
        if (gr < kk) {
            int g = rows[j];
            v = (double)(x[b * DD + g] - mu[g]);
        }
        rz[j] = v;
    }

    double q_acc = 0.0;
    double dsave = 1.0;

    const int npan = (kk + 7) >> 3;
    for (int p = 0; p < npan; ++p) {
        const int rem = kk - 8 * p;
        const int jmax = (rem + 7) >> 3;

        #pragma unroll
        for (int tt = 0; tt < 8; ++tt) {
            if (tt < rem) {
                const int t = 8 * p + tt;

                // ---- owners publish pivot column t (post-previous-pivot) --
                if (lc == tt) {
                    #pragma unroll
                    for (int j = 0; j < 8; ++j)
                        if (j < jmax) colbuf[wid][8 * j + lr] = T[j][0];
                }
                __asm__ __volatile__("" ::: "memory");   // writes before reads

                double dp = colbuf[wid][tt];             // broadcast read
                double inv = 1.0 / dp;
                double rzt = __shfl(rz[0], tt);
                if (lane == t) dsave = dp;
                q_acc = fma(rzt * inv, rzt, q_acc);

                // ---- broadcast reads: row and col values of column t ------
                double arow[8], acol[8];
                #pragma unroll
                for (int j = 0; j < 8; ++j)
                    arow[j] = (j < jmax) ? colbuf[wid][8 * j + lr] : 0.0;
                #pragma unroll
                for (int m = 0; m < 8; ++m)
                    acol[m] = (m < jmax) ? colbuf[wid][8 * m + lc] : 0.0;
                __asm__ __volatile__("" ::: "memory");   // reads before next writes

                #pragma unroll
                for (int j = 0; j < 8; ++j) {
                    if (j < jmax) {
                        double aj = arow[j] * inv;
                        #pragma unroll
                        for (int m = 0; m <= j; ++m)
                            T[j][m] = fma(-aj, acol[m], T[j][m]);
                        rz[j] = fma(-aj, rzt, rz[j]);
                    }
                }
            }
        }
        #pragma unroll
        for (int j = 0; j < 7; ++j) {
            #pragma unroll
            for (int m = 0; m <= j; ++m)
                T[j][m] = T[j + 1][m + 1];
            rz[j] = rz[j + 1];
        }
    }

    double ld = log(dsave);
    for (int off = 32; off; off >>= 1)
        ld += __shfl_down(ld, off);
    if (lane == 0)
        out[b] = (float)(0.5 * (q_acc + ld + (double)kk * LOG_2PI));
}

// ---------------------------------------------------------------------------
// Kernel 2b: merged straggler kernel (single dispatch). One wave per block.
// kk <= 72: 9-slot shfl register tile (R4-passing version, unchanged).
// kk > 72 (never observed): staged-LDS safety net.
// ---------------------------------------------------------------------------
__global__ __launch_bounds__(64, 1) void nll_kernel_straggler(
    const float* __restrict__ x,
    const int*   __restrict__ mask,
    const float* __restrict__ mu,
    const double* __restrict__ cov,
    float* __restrict__ out,
    const int* __restrict__ bigcount,
    const int* __restrict__ biglist)
{
    __shared__ int obs[DD];
    __shared__ double S[NPACK];     // used only on the kk>72 path
    __shared__ double colS[DD];
    __shared__ double rzS[DD];

    int nbig = *bigcount;
    if (nbig > BIGCAP) nbig = BIGCAP;
    if ((int)blockIdx.x >= nbig) return;
    const int b = biglist[blockIdx.x];

    const int lane = threadIdx.x;
    const int lr = lane & 7;
    const int lc = lane >> 3;

    int i1 = lane + 64;
    int m0 = (mask[b * DD + lane] != 0);
    int m1v = (i1 < DD) ? (mask[b * DD + i1] != 0) : 0;
    unsigned long long b0 = __ballot(m0);
    unsigned long long bb1 = __ballot(m1v);
    unsigned long long lowmask = (1ull << lane) - 1ull;
    int k0 = __popcll(b0);
    int pos0 = __popcll(b0 & lowmask);
    int pos1 = k0 + __popcll(bb1 & lowmask);
    const int kk = k0 + __popcll(bb1);
    if (m0) obs[pos0] = lane;
    if (m1v) obs[pos1] = i1;
    __syncthreads();

    if (kk <= R2CAP) {
        // ---------------- 9-slot register path ----------
        if (lane == 0)
            for (int t = kk; t < R2CAP; ++t) obs[t] = 0;
        __syncthreads();

        int rows[9], cols[9];
        #pragma unroll
        for (int j = 0; j < 9; ++j) rows[j] = obs[8 * j + lr];
        #pragma unroll
        for (int m = 0; m < 9; ++m) cols[m] = obs[8 * m + lc];

        double T[9][9];
        #pragma unroll
        for (int j = 0; j < 9; ++j) {
            const int gr = 8 * j + lr;
            #pragma unroll
            for (int m = 0; m <= j; ++m) {
                const int gc = 8 * m + lc;
                double v = 0.0;
                if (gr < kk && gc <= gr) {
                    v = cov[rows[j] * DD + cols[m]];
                    if (gr == gc) v += JITTER;
                }
                T[j][m] = v;
            }
        }

        double rz[9];
        #pragma unroll
        for (int j = 0; j < 9; ++j) {
            const int gr = 8 * j + lr;
            double v = 0.0;
            if (gr < kk) {
                int g = rows[j];
                v = (double)(x[b * DD + g] - mu[g]);
            }
            rz[j] = v;
        }

        double q_acc = 0.0;
        double dsave = 1.0, dsave2 = 1.0;

        const int npan = (kk + 7) >> 3;
        for (int p = 0; p < npan; ++p) {
            const int rem = kk - 8 * p;
            const int jmax = (rem + 7) >> 3;

            double dp  = __shfl(T[0][0], 0);
            double inv = 1.0 / dp;

            #pragma unroll
            for (int tt = 0; tt < 8; ++tt) {
                if (tt < rem) {
                    const int t = 8 * p + tt;

                    double rzt = __shfl(rz[0], tt);
                    if (lane == t) dsave = dp;
                    if (lane + 64 == t) dsave2 = dp;
                    q_acc = fma(rzt * inv, rzt, q_acc);

                    double dp_next = 0.0, inv_next = 0.0;
                    if (tt < 7) {
                        double dnA = __shfl(T[0][0], 9 * (tt + 1));
                        double dnB = __shfl(T[0][0], 9 * tt + 1);
                        double aj_lk = dnB * inv;
                        dp_next = fma(-aj_lk, dnB, dnA);
                        inv_next = 1.0 / dp_next;
                    }

                    double cc[9];
                    #pragma unroll
                    for (int m = 0; m < 9; ++m)
                        cc[m] = (m < jmax)
                              ? __shfl(T[m][0], 8 * tt + lc) : 0.0;

                    #pragma unroll
                    for (int j = 0; j < 9; ++j) {
                        if (j < jmax) {
                            double aj = __shfl(T[j][0], 8 * tt + lr) * inv;
                            #pragma unroll
                            for (int m = 0; m <= j; ++m)
                                T[j][m] = fma(-aj, cc[m], T[j][m]);
                            rz[j] = fma(-aj, rzt, rz[j]);
                        }
                    }

                    if (tt < 7) { dp = dp_next; inv = inv_next; }
                }
            }
            #pragma unroll
            for (int j = 0; j < 8; ++j) {
                #pragma unroll
                for (int m = 0; m <= j; ++m)
                    T[j][m] = T[j + 1][m + 1];
                rz[j] = rz[j + 1];
            }
        }

        double ld = log(dsave) + log(dsave2);
        for (int off = 32; off; off >>= 1)
            ld += __shfl_down(ld, off);
        if (lane == 0)
            out[b] = (float)(0.5 * (q_acc + ld + (double)kk * LOG_2PI));
        return;
    }

    // ---------------- kk > 72: staged-LDS path (safety net) ----------------
    for (int i = lane; i < kk; i += 64) {
        int g = obs[i];
        rzS[i] = (double)(x[b * DD + g] - mu[g]);
    }
    int T2 = kk * (kk + 1) / 2;
    for (int t = lane; t < T2; t += 64) {
        int i = (int)((sqrt(8.0 * (double)t + 1.0) - 1.0) * 0.5);
        while ((i + 1) * (i + 2) / 2 <= t) ++i;
        while (i * (i + 1) / 2 > t) --i;
        int j = t - i * (i + 1) / 2;
        double val = cov[obs[i] * DD + obs[j]];
        if (i == j) val += JITTER;
        S[t] = val;
    }
    __syncthreads();

    for (int p = 0; p < kk; ++p) {
        for (int l = p + lane; l < kk; l += 64)
            colS[l] = S[l * (l + 1) / 2 + p];
        __syncthreads();
        double inv = 1.0 / colS[p];
        double rzp = rzS[p];
        for (int i = p + 1 + lane; i < kk; i += 64) {
            double* Srow = S + i * (i + 1) / 2;
            double ai = colS[i] * inv;
            #pragma unroll 4
            for (int l = p + 1; l <= i; ++l)
                Srow[l] -= ai * colS[l];
            rzS[i] -= ai * rzp;
        }
        __syncthreads();
    }

    double q = 0.0, ld = 0.0;
    for (int j = lane; j < kk; j += 64) {
        double dj = S[j * (j + 1) / 2 + j];
        ld += log(dj);
        double zj = rzS[j];
        q += zj * zj / dj;
    }
    for (int off = 32; off; off >>= 1) {
        q  += __shfl_down(q, off);
        ld += __shfl_down(ld, off);
    }
    if (lane == 0)
        out[b] = (float)(0.5 * (q + ld + (double)kk * LOG_2PI));
}

// ---------------------------------------------------------------------------
extern "C" void kernel_launch(void* const* d_in, const int* in_sizes, int n_in,
                              void* d_out, int out_size, void* d_ws, size_t ws_size,
                              hipStream_t stream)
{
    const float* x         = (const float*)d_in[0];
    const int*   mask      = (const int*)d_in[1];
    const float* mu        = (const float*)d_in[2];
    const float* log_diag  = (const float*)d_in[3];
    const float* lower_tri = (const float*)d_in[4];
    float* out = (float*)d_out;

    double* cov    = (double*)d_ws;                            // 80000 B
    int* counters  = (int*)((char*)d_ws + 80000);              // 4 B
    int* biglist   = (int*)((char*)d_ws + 80128);              // BIGCAP*4

    const int Bn = in_sizes[0] / DD;

    build_cov_kernel<<<(DD * DD + 255) / 256, 256, 0, stream>>>(
        log_diag, lower_tri, cov, counters);
    nll_kernel_tile<<<(Bn + WPB - 1) / WPB, 256, 0, stream>>>(
        x, mask, mu, cov, out, counters, biglist, Bn);
    nll_kernel_straggler<<<32, 64, 0, stream>>>(
        x, mask, mu, cov, out, counters, biglist);
}

// Round 6
// 190.248 us; speedup vs baseline: 1.0770x; 1.0770x over previous
//
#include <hip/hip_runtime.h>
#include <math.h>

#define DD 100
#define NTRIL 4950                 // D*(D-1)/2
#define NPACK (DD * (DD + 1) / 2)  // 5050
#define LOG_2PI 1.8378770664093453
#define JITTER 5.5e-8              // calibrated vs np twin (R7-R9 probes)
#define RCAP 64                    // tier-1 register tile capacity
#define R2CAP 72                   // straggler 9-slot register tile capacity
#define WPB 4                      // waves (samples) per block in tier 1
#define BIGCAP 256                 // straggler list capacity (ws layout)

// ---------------------------------------------------------------------------
// Kernel 1: cov = A * A^T in fp64 (exact). Zeroes the straggler counter.
// ---------------------------------------------------------------------------
__global__ __launch_bounds__(256) void build_cov_kernel(
    const float* __restrict__ log_diag,
    const float* __restrict__ lower_tri,
    double* __restrict__ cov,
    int* __restrict__ counters)
{
    if (blockIdx.x == 0 && threadIdx.x == 0)
        counters[0] = 0;
    __shared__ double sLow[NTRIL];
    __shared__ double sDiag[DD];
    for (int t = threadIdx.x; t < NTRIL; t += blockDim.x)
        sLow[t] = (double)lower_tri[t];
    for (int t = threadIdx.x; t < DD; t += blockDim.x)
        sDiag[t] = exp((double)log_diag[t]);
    __syncthreads();

    int idx = blockIdx.x * blockDim.x + threadIdx.x;
    if (idx >= DD * DD) return;
    int i = idx / DD;
    int j = idx % DD;
    int mn = (i < j) ? i : j;
    int bi = i * (i - 1) / 2;
    int bj = j * (j - 1) / 2;
    double acc = 0.0;
    for (int t = 0; t < mn; ++t)
        acc += sLow[bi + t] * sLow[bj + t];
    double ai = (mn < i) ? sLow[bi + mn] : sDiag[i];
    double aj = (mn < j) ? sLow[bj + mn] : sDiag[j];
    cov[idx] = acc + ai * aj;
}

// ---------------------------------------------------------------------------
// Kernel 2a (tier 1): CONTIGUOUS-SUB-TILE register LDL^T, kk <= 64.
// Four samples/block, one sample per wave.
//
// Resource model (R1/R4/R5 postmortems): binding pipe = per-CU DS unit.
// Old 8x8-interleaved layout needed ~30 narrow/bank-aliased DS ops per
// pivot (b64 crossbar bpermutes or stride-64B b64 reads aliasing to 2
// banks). New mapping: lane (R,C) = (lane>>3, lane&7) owns contiguous
// sub-tile A[8R..8R+7, 8C..8C+7]. Per pivot t (tb=t>>3, tc=t&7):
//   - owner lanes (C==tb) publish pivot column: 4 masked ds_write_b128
//     into colw[] padded to stride 10 (banks (20R+4k)%32 all distinct ->
//     conflict-free);
//   - every lane reads its row-slice colw[10R..+7] and col-slice
//     colw[10C..+7] (symmetry A[t,u]=A[u,t]): 8 ds_read_b128, 8-lane
//     same-address broadcasts, conflict-free;
//   - d and z_t: scalar broadcast reads. NO __shfl in the loop.
// ~15 wide DS ops vs ~30 narrow: DS cycles ~4x down; VALU (72 f64 FMA
// full-square update) becomes the binding pipe.
// Dead-region updates (rows/cols < t or >= kk) are dead->dead dataflow;
// live arithmetic is op-for-op identical to the verified kernel
// (lj = ar[j]*inv; T -= lj*ac[m]; z -= lj*zt; q += (zt*inv)*zt; dsave at
// lane==t; same log+shfl_down reduce).
// R19 lesson: same-wave LDS write->read is HW-ordered (in-order per-wave
// DS queue); asm volatile("" ::: "memory") fences stop COMPILER reorder.
// All register arrays statically indexed (tc unrolled — scratch rule).
// ---------------------------------------------------------------------------
__global__ __launch_bounds__(256, 2) void nll_kernel_tile(
    const float* __restrict__ x,
    const int*   __restrict__ mask,
    const float* __restrict__ mu,
    const double* __restrict__ cov,
    float* __restrict__ out,
    int* __restrict__ bigcount,
    int* __restrict__ biglist,
    int Bn)
{
    __shared__ int obs[WPB][RCAP];
    __shared__ __align__(16) double colw[WPB][82];  // [80]=z_t, stride-10 rows

    const int wid  = threadIdx.x >> 6;
    const int lane = threadIdx.x & 63;
    const int b = blockIdx.x * WPB + wid;
    if (b >= Bn) return;

    const int R = lane >> 3;
    const int C = lane & 7;

    int i1 = lane + 64;
    int m0 = (mask[b * DD + lane] != 0);
    int m1v = (i1 < DD) ? (mask[b * DD + i1] != 0) : 0;
    unsigned long long b0 = __ballot(m0);
    unsigned long long bb1 = __ballot(m1v);
    unsigned long long lowmask = (1ull << lane) - 1ull;
    int k0 = __popcll(b0);
    int pos0 = __popcll(b0 & lowmask);
    int pos1 = k0 + __popcll(bb1 & lowmask);
    const int kk = k0 + __popcll(bb1);
    if (m0 && pos0 < RCAP) obs[wid][pos0] = lane;
    if (m1v && pos1 < RCAP) obs[wid][pos1] = i1;
    if (lane >= kk && lane < RCAP) obs[wid][lane] = 0;
    __syncthreads();
    if (kk > RCAP) {                   // straggler: enqueue, bail (wave-uniform)
        if (lane == 0) {
            int idx = atomicAdd(bigcount, 1);
            if (idx < BIGCAP) biglist[idx] = b;
        }
        return;
    }

    int rows[8], cols[8];
    #pragma unroll
    for (int j = 0; j < 8; ++j) rows[j] = obs[wid][8 * R + j];
    #pragma unroll
    for (int m = 0; m < 8; ++m) cols[m] = obs[wid][8 * C + m];

    // Full 8x8 sub-tile load (cov is bit-exactly symmetric by construction).
    double T[8][8];
    #pragma unroll
    for (int j = 0; j < 8; ++j) {
        const int gr = 8 * R + j;
        #pragma unroll
        for (int m = 0; m < 8; ++m) {
            const int gc = 8 * C + m;
            double v = 0.0;
            if (gr < kk && gc < kk) {
                v = cov[rows[j] * DD + cols[m]];
                if (gr == gc) v += JITTER;
            }
            T[j][m] = v;
        }
    }

    // z replicated across the 8 lanes of each row-group R.
    double z[8];
    #pragma unroll
    for (int j = 0; j < 8; ++j) {
        const int gr = 8 * R + j;
        double v = 0.0;
        if (gr < kk) {
            int g = rows[j];
            v = (double)(x[b * DD + g] - mu[g]);
        }
        z[j] = v;
    }

    double q_acc = 0.0;
    double dsave = 1.0;

    for (int tb = 0; tb < 8; ++tb) {
        if (8 * tb >= kk) break;                  // wave-uniform
        #pragma unroll
        for (int tc = 0; tc < 8; ++tc) {
            const int t = 8 * tb + tc;
            if (t < kk) {                         // wave-uniform
                // ---- owners publish pivot column t (4 x b128, masked) ----
                if (C == tb) {
                    double2* pw = (double2*)&colw[wid][10 * R];
                    double2 w0; w0.x = T[0][tc]; w0.y = T[1][tc]; pw[0] = w0;
                    double2 w1; w1.x = T[2][tc]; w1.y = T[3][tc]; pw[1] = w1;
                    double2 w2; w2.x = T[4][tc]; w2.y = T[5][tc]; pw[2] = w2;
                    double2 w3; w3.x = T[6][tc]; w3.y = T[7][tc]; pw[3] = w3;
                }
                if (lane == t) colw[wid][80] = z[tc];
                __asm__ __volatile__("" ::: "memory");  // writes before reads

                double d   = colw[wid][10 * tb + tc];   // broadcast
                double zt  = colw[wid][80];             // broadcast
                double inv = 1.0 / d;
                if (lane == t) dsave = d;
                q_acc = fma(zt * inv, zt, q_acc);

                // ---- row-slice and col-slice reads (8 x b128, bcast) -----
                double ar[8], ac[8];
                const double2* pr = (const double2*)&colw[wid][10 * R];
                const double2* pc = (const double2*)&colw[wid][10 * C];
                #pragma unroll
                for (int k2 = 0; k2 < 4; ++k2) {
                    double2 va = pr[k2];
                    ar[2 * k2]     = va.x;
                    ar[2 * k2 + 1] = va.y;
                    double2 vb = pc[k2];
                    ac[2 * k2]     = vb.x;
                    ac[2 * k2 + 1] = vb.y;
                }
                __asm__ __volatile__("" ::: "memory");  // reads before next writes

                // ---- rank-1 update, op-order identical to verified kernel -
                #pragma unroll
                for (int j = 0; j < 8; ++j) {
                    double lj = ar[j] * inv;
                    #pragma unroll
                    for (int m = 0; m < 8; ++m)
                        T[j][m] = fma(-lj, ac[m], T[j][m]);
                    z[j] = fma(-lj, zt, z[j]);
                }
            }
        }
    }

    double ld = log(dsave);
    for (int off = 32; off; off >>= 1)
        ld += __shfl_down(ld, off);
    if (lane == 0)
        out[b] = (float)(0.5 * (q_acc + ld + (double)kk * LOG_2PI));
}

// ---------------------------------------------------------------------------
// Kernel 2b: merged straggler kernel (single dispatch). One wave per block.
// kk <= 72: 9-slot shfl register tile (R4/R5-passing version, unchanged).
// kk > 72 (never observed): staged-LDS safety net.
// ---------------------------------------------------------------------------
__global__ __launch_bounds__(64, 1) void nll_kernel_straggler(
    const float* __restrict__ x,
    const int*   __restrict__ mask,
    const float* __restrict__ mu,
    const double* __restrict__ cov,
    float* __restrict__ out,
    const int* __restrict__ bigcount,
    const int* __restrict__ biglist)
{
    __shared__ int obs[DD];
    __shared__ double S[NPACK];     // used only on the kk>72 path
    __shared__ double colS[DD];
    __shared__ double rzS[DD];

    int nbig = *bigcount;
    if (nbig > BIGCAP) nbig = BIGCAP;
    if ((int)blockIdx.x >= nbig) return;
    const int b = biglist[blockIdx.x];

    const int lane = threadIdx.x;
    const int lr = lane & 7;
    const int lc = lane >> 3;

    int i1 = lane + 64;
    int m0 = (mask[b * DD + lane] != 0);
    int m1v = (i1 < DD) ? (mask[b * DD + i1] != 0) : 0;
    unsigned long long b0 = __ballot(m0);
    unsigned long long bb1 = __ballot(m1v);
    unsigned long long lowmask = (1ull << lane) - 1ull;
    int k0 = __popcll(b0);
    int pos0 = __popcll(b0 & lowmask);
    int pos1 = k0 + __popcll(bb1 & lowmask);
    const int kk = k0 + __popcll(bb1);
    if (m0) obs[pos0] = lane;
    if (m1v) obs[pos1] = i1;
    __syncthreads();

    if (kk <= R2CAP) {
        // ---------------- 9-slot register path ----------
        if (lane == 0)
            for (int t = kk; t < R2CAP; ++t) obs[t] = 0;
        __syncthreads();

        int rows[9], cols[9];
        #pragma unroll
        for (int j = 0; j < 9; ++j) rows[j] = obs[8 * j + lr];
        #pragma unroll
        for (int m = 0; m < 9; ++m) cols[m] = obs[8 * m + lc];

        double T[9][9];
        #pragma unroll
        for (int j = 0; j < 9; ++j) {
            const int gr = 8 * j + lr;
            #pragma unroll
            for (int m = 0; m <= j; ++m) {
                const int gc = 8 * m + lc;
                double v = 0.0;
                if (gr < kk && gc <= gr) {
                    v = cov[rows[j] * DD + cols[m]];
                    if (gr == gc) v += JITTER;
                }
                T[j][m] = v;
            }
        }

        double rz[9];
        #pragma unroll
        for (int j = 0; j < 9; ++j) {
            const int gr = 8 * j + lr;
            double v = 0.0;
            if (gr < kk) {
                int g = rows[j];
                v = (double)(x[b * DD + g] - mu[g]);
            }
            rz[j] = v;
        }

        double q_acc = 0.0;
        double dsave = 1.0, dsave2 = 1.0;

        const int npan = (kk + 7) >> 3;
        for (int p = 0; p < npan; ++p) {
            const int rem = kk - 8 * p;
            const int jmax = (rem + 7) >> 3;

            double dp  = __shfl(T[0][0], 0);
            double inv = 1.0 / dp;

            #pragma unroll
            for (int tt = 0; tt < 8; ++tt) {
                if (tt < rem) {
                    const int t = 8 * p + tt;

                    double rzt = __shfl(rz[0], tt);
                    if (lane == t) dsave = dp;
                    if (lane + 64 == t) dsave2 = dp;
                    q_acc = fma(rzt * inv, rzt, q_acc);

                    double dp_next = 0.0, inv_next = 0.0;
                    if (tt < 7) {
                        double dnA = __shfl(T[0][0], 9 * (tt + 1));
                        double dnB = __shfl(T[0][0], 9 * tt + 1);
                        double aj_lk = dnB * inv;
                        dp_next = fma(-aj_lk, dnB, dnA);
                        inv_next = 1.0 / dp_next;
                    }

                    double cc[9];
                    #pragma unroll
                    for (int m = 0; m < 9; ++m)
                        cc[m] = (m < jmax)
                              ? __shfl(T[m][0], 8 * tt + lc) : 0.0;

                    #pragma unroll
                    for (int j = 0; j < 9; ++j) {
                        if (j < jmax) {
                            double aj = __shfl(T[j][0], 8 * tt + lr) * inv;
                            #pragma unroll
                            for (int m = 0; m <= j; ++m)
                                T[j][m] = fma(-aj, cc[m], T[j][m]);
                            rz[j] = fma(-aj, rzt, rz[j]);
                        }
                    }

                    if (tt < 7) { dp = dp_next; inv = inv_next; }
                }
            }
            #pragma unroll
            for (int j = 0; j < 8; ++j) {
                #pragma unroll
                for (int m = 0; m <= j; ++m)
                    T[j][m] = T[j + 1][m + 1];
                rz[j] = rz[j + 1];
            }
        }

        double ld = log(dsave) + log(dsave2);
        for (int off = 32; off; off >>= 1)
            ld += __shfl_down(ld, off);
        if (lane == 0)
            out[b] = (float)(0.5 * (q_acc + ld + (double)kk * LOG_2PI));
        return;
    }

    // ---------------- kk > 72: staged-LDS path (safety net) ----------------
    for (int i = lane; i < kk; i += 64) {
        int g = obs[i];
        rzS[i] = (double)(x[b * DD + g] - mu[g]);
    }
    int T2 = kk * (kk + 1) / 2;
    for (int t = lane; t < T2; t += 64) {
        int i = (int)((sqrt(8.0 * (double)t + 1.0) - 1.0) * 0.5);
        while ((i + 1) * (i + 2) / 2 <= t) ++i;
        while (i * (i + 1) / 2 > t) --i;
        int j = t - i * (i + 1) / 2;
        double val = cov[obs[i] * DD + obs[j]];
        if (i == j) val += JITTER;
        S[t] = val;
    }
    __syncthreads();

    for (int p = 0; p < kk; ++p) {
        for (int l = p + lane; l < kk; l += 64)
            colS[l] = S[l * (l + 1) / 2 + p];
        __syncthreads();
        double inv = 1.0 / colS[p];
        double rzp = rzS[p];
        for (int i = p + 1 + lane; i < kk; i += 64) {
            double* Srow = S + i * (i + 1) / 2;
            double ai = colS[i] * inv;
            #pragma unroll 4
            for (int l = p + 1; l <= i; ++l)
                Srow[l] -= ai * colS[l];
            rzS[i] -= ai * rzp;
        }
        __syncthreads();
    }

    double q = 0.0, ld = 0.0;
    for (int j = lane; j < kk; j += 64) {
        double dj = S[j * (j + 1) / 2 + j];
        ld += log(dj);
        double zj = rzS[j];
        q += zj * zj / dj;
    }
    for (int off = 32; off; off >>= 1) {
        q  += __shfl_down(q, off);
        ld += __shfl_down(ld, off);
    }
    if (lane == 0)
        out[b] = (float)(0.5 * (q + ld + (double)kk * LOG_2PI));
}

// ---------------------------------------------------------------------------
extern "C" void kernel_launch(void* const* d_in, const int* in_sizes, int n_in,
                              void* d_out, int out_size, void* d_ws, size_t ws_size,
                              hipStream_t stream)
{
    const float* x         = (const float*)d_in[0];
    const int*   mask      = (const int*)d_in[1];
    const float* mu        = (const float*)d_in[2];
    const float* log_diag  = (const float*)d_in[3];
    const float* lower_tri = (const float*)d_in[4];
    float* out = (float*)d_out;

    double* cov    = (double*)d_ws;                            // 80000 B
    int* counters  = (int*)((char*)d_ws + 80000);              // 4 B
    int* biglist   = (int*)((char*)d_ws + 80128);              // BIGCAP*4

    const int Bn = in_sizes[0] / DD;

    build_cov_kernel<<<(DD * DD + 255) / 256, 256, 0, stream>>>(
        log_diag, lower_tri, cov, counters);
    nll_kernel_tile<<<(Bn + WPB - 1) / WPB, 256, 0, stream>>>(
        x, mask, mu, cov, out, counters, biglist, Bn);
    nll_kernel_straggler<<<32, 64, 0, stream>>>(
        x, mask, mu, cov, out, counters, biglist);
}